// Round 9
// baseline (217.566 us; speedup 1.0000x reference)
//
#include <hip/hip_runtime.h>
#include <hip/hip_bf16.h>

#define B_ROWS 4096
#define TWOB   8192
#define DIM    256
#define INV_T  14.285714285714286f   // 1/0.07
#define EXPSCALE 20.609865074705232f // (1/0.07) * log2(e) -> exp2f

#define BM 128
#define BN 128
#define NSTRIP 8
#define CT_PER_STRIP 8    // (8192/128)/NSTRIP
#define NBLK 512          // 64 rt * 8 strips; LDS 80 KB -> exactly 2 blocks/CU co-resident

typedef __bf16 bf16x8 __attribute__((ext_vector_type(8)));   // 16 bytes
typedef float  f32x4  __attribute__((ext_vector_type(4)));

// Software grid barrier (cooperative launch failed in R8 — unchecked validator
// reject). Device-scope atomics; tid0's __threadfence() emits the L2
// writeback/invalidate needed for cross-XCD visibility (gfx950 agent-scope
// fence), __syncthreads() orders the whole block around it. Counters are
// zeroed by a hipMemsetAsync graph node before the kernel. Safe only because
// grid (512) <= co-resident capacity (2 blocks/CU x 256 CU, LDS-bound).
__device__ __forceinline__ void gbar(unsigned int* cnt) {
    __syncthreads();
    if (threadIdx.x == 0) {
        __threadfence();                     // release: wb L2 (zn/strip_sums visible)
        atomicAdd(cnt, 1u);
        while (atomicAdd(cnt, 0u) < NBLK) __builtin_amdgcn_s_sleep(8);
        __threadfence();                     // acquire: inv L1/L2
    }
    __syncthreads();
}

// ---------------- fused NT-Xent: normalize -> flash GEMM -> finalize ----------------
// One kernel, 512 blocks x 256 threads. Kills the measured ~57 us fixed
// overhead of the 3-kernel pipeline (56.8/56.9/57.4/56.9 us across R2/3/5/7).
// Phase B == R5's verified structure: A-tile (128x256 = 64 KB) LDS-resident,
// B ping-pong (2x8 KB), stage(it+1) issued right after the single barrier so
// the next barrier's vmcnt(0) drain is covered by a full compute phase.
__global__ __launch_bounds__(256) void ntxent_fused(const float* __restrict__ zi,
                                                    const float* __restrict__ zj,
                                                    unsigned short* __restrict__ znu,
                                                    float* __restrict__ pos,
                                                    float* __restrict__ strip_sums,
                                                    unsigned int* __restrict__ ctrl,  // [0..2]=barriers, [3]=loss bits (memset 0)
                                                    float* __restrict__ out) {
    __shared__ __attribute__((aligned(16))) __bf16 As[8][BM * 32];   // 64 KB
    __shared__ __attribute__((aligned(16))) __bf16 Bs[2][BN * 32];   // 16 KB

    const int tid  = threadIdx.x;
    const int wave = tid >> 6;
    const int lane = tid & 63;
    const int bid  = blockIdx.x;
    float* loss_acc = (float*)(ctrl + 3);

    // ================= phase A: row L2-normalize, fp32 -> bf16 =================
    // 512 blocks x 16 rows; each wave does 4 rows (64 lanes x float4 = 256 elems).
    {
        const int base = bid * 16 + wave * 4;
#pragma unroll
        for (int i = 0; i < 4; ++i) {
            const int row = base + i;
            const float* src = (row < B_ROWS) ? (zi + (size_t)row * DIM)
                                              : (zj + (size_t)(row - B_ROWS) * DIM);
            float4 v = reinterpret_cast<const float4*>(src)[lane];
            float ss = v.x * v.x + v.y * v.y + v.z * v.z + v.w * v.w;
#pragma unroll
            for (int off = 32; off >= 1; off >>= 1) ss += __shfl_xor(ss, off);
            float inv = 1.0f / fmaxf(sqrtf(ss), 1e-8f);   // COS_EPS
            ushort4 o;
            o.x = __builtin_bit_cast(unsigned short, __float2bfloat16(v.x * inv));
            o.y = __builtin_bit_cast(unsigned short, __float2bfloat16(v.y * inv));
            o.z = __builtin_bit_cast(unsigned short, __float2bfloat16(v.z * inv));
            o.w = __builtin_bit_cast(unsigned short, __float2bfloat16(v.w * inv));
            reinterpret_cast<ushort4*>(znu)[(size_t)row * 64 + lane] = o;
        }
    }
    gbar(ctrl + 0);

    // ================= phase B: flash GEMM + exp row-sums (R5 structure) =======
    const __bf16* zn = (const __bf16*)znu;
    const int wr = wave >> 1, wc = wave & 1;
    const int quad = lane >> 4, lc = lane & 15;
    const int rt    = bid >> 3;          // row-tile 0..63
    const int strip = bid & 7;           // 0..NSTRIP-1
    const int row0  = rt * BM;
    const int posTile = (rt + 32) & 63;  // col-tile holding (row+4096) mod 8192

    // staging: per-lane global element offsets for this wave's two 1KB chunks.
    // chunk c = j*64+lane -> (m=c>>2, kc_lds=c&3); source kc_g = kc_lds ^ sw(m)
    int stg_off[2];
#pragma unroll
    for (int t = 0; t < 2; ++t) {
        int c  = (wave * 2 + t) * 64 + lane;
        int m  = c >> 2;
        int kc = (c & 3) ^ ((m & 3) ^ ((m >> 2) & 3));
        stg_off[t] = m * DIM + kc * 8;
    }

    // fragment-read byte offsets within one 8KB chunk (swizzle depends on m&15 == lc)
    const int sw    = (lc & 3) ^ ((lc >> 2) & 3);
    const int aBase = (wr * 64 + lc) * 64 + ((quad ^ sw) * 16);
    const int bBase = (wc * 64 + lc) * 64 + ((quad ^ sw) * 16);

    // prologue: stage full A (8 chunks) + first B chunk
#pragma unroll
    for (int kt = 0; kt < 8; ++kt) {
#pragma unroll
        for (int t = 0; t < 2; ++t) {
            const int j = wave * 2 + t;
            const __bf16* ga = zn + row0 * DIM + kt * 32 + stg_off[t];
            __builtin_amdgcn_global_load_lds(
                (const __attribute__((address_space(1))) void*)ga,
                (__attribute__((address_space(3))) void*)((char*)As + kt * 8192 + j * 1024), 16, 0, 0);
        }
    }
    {
        const int col0 = strip * CT_PER_STRIP * BN;
#pragma unroll
        for (int t = 0; t < 2; ++t) {
            const int j = wave * 2 + t;
            const __bf16* gb = zn + col0 * DIM + stg_off[t];
            __builtin_amdgcn_global_load_lds(
                (const __attribute__((address_space(1))) void*)gb,
                (__attribute__((address_space(3))) void*)((char*)Bs + j * 1024), 16, 0, 0);
        }
    }

    f32x4 acc[4][4];
    float rsum[4][4];
#pragma unroll
    for (int mi = 0; mi < 4; ++mi)
#pragma unroll
        for (int r = 0; r < 4; ++r) rsum[mi][r] = 0.0f;

    for (int ct = 0; ct < CT_PER_STRIP; ++ct) {
        const int colTile = strip * CT_PER_STRIP + ct;
        const int col0 = colTile * BN;
#pragma unroll
        for (int mi = 0; mi < 4; ++mi)
#pragma unroll
            for (int ni = 0; ni < 4; ++ni) acc[mi][ni] = f32x4{0.f, 0.f, 0.f, 0.f};

#pragma unroll
        for (int kt = 0; kt < 8; ++kt) {
            // barrier: (a) drains the B stage issued one iteration ago (covered
            // by that iteration's compute), (b) guards reuse of Bs[kt+1 & 1].
            __syncthreads();
            {
                const int nct = (kt == 7) ? ct + 1 : ct;
                const int nkt = (kt + 1) & 7;
                if (nct < CT_PER_STRIP) {
                    const int ncol0 = (strip * CT_PER_STRIP + nct) * BN;
#pragma unroll
                    for (int t = 0; t < 2; ++t) {
                        const int j = wave * 2 + t;
                        const __bf16* gb = zn + ncol0 * DIM + nkt * 32 + stg_off[t];
                        __builtin_amdgcn_global_load_lds(
                            (const __attribute__((address_space(1))) void*)gb,
                            (__attribute__((address_space(3))) void*)((char*)Bs + ((kt + 1) & 1) * 8192 + j * 1024),
                            16, 0, 0);
                    }
                }
            }

            bf16x8 af[4], bfr[4];
#pragma unroll
            for (int mi = 0; mi < 4; ++mi)
                af[mi] = *(const bf16x8*)((const char*)As + kt * 8192 + aBase + mi * 1024);
#pragma unroll
            for (int ni = 0; ni < 4; ++ni)
                bfr[ni] = *(const bf16x8*)((const char*)Bs + (kt & 1) * 8192 + bBase + ni * 1024);
#pragma unroll
            for (int mi = 0; mi < 4; ++mi)
#pragma unroll
                for (int ni = 0; ni < 4; ++ni)
                    acc[mi][ni] = __builtin_amdgcn_mfma_f32_16x16x32_bf16(
                        af[mi], bfr[ni], acc[mi][ni], 0, 0, 0);
        }

        // epilogue: exp + running row sums (C/D: row = quad*4+reg, col = lc).
        // Runs while the B(ct+1, kt=0) stage is in flight.
        const bool special = (colTile == rt) || (colTile == posTile);
#pragma unroll
        for (int mi = 0; mi < 4; ++mi) {
#pragma unroll
            for (int ni = 0; ni < 4; ++ni) {
                f32x4 a = acc[mi][ni];
#pragma unroll
                for (int r = 0; r < 4; ++r) {
                    float e = exp2f(a[r] * EXPSCALE);    // exp(s/T)
                    if (special) {
                        int gr = row0 + wr * 64 + mi * 16 + quad * 4 + r;
                        int gc = col0 + wc * 64 + ni * 16 + lc;
                        if (gc == ((gr + B_ROWS) & (TWOB - 1))) pos[gr] = a[r] * INV_T;
                        if (gr == gc) e = 0.0f;          // diagonal mask
                    }
                    rsum[mi][r] += e;
                }
            }
        }
    }

    // all MFMA/ds_reads of As done; alias rowsumL onto As (stay at 80 KB)
    __syncthreads();
    float* rowsumL = (float*)As;         // [2][BM]
#pragma unroll
    for (int mi = 0; mi < 4; ++mi) {
#pragma unroll
        for (int r = 0; r < 4; ++r) {
            float v = rsum[mi][r];
            v += __shfl_xor(v, 1);
            v += __shfl_xor(v, 2);
            v += __shfl_xor(v, 4);
            v += __shfl_xor(v, 8);
            if (lc == 0) rowsumL[wc * BM + wr * 64 + mi * 16 + quad * 4 + r] = v;
        }
    }
    __syncthreads();
    if (tid < BM)
        strip_sums[(size_t)strip * TWOB + row0 + tid] = rowsumL[tid] + rowsumL[BM + tid];

    gbar(ctrl + 1);

    // ================= phase C: loss = mean(log(sumexp) - pos) =================
    // 512 blocks x 16 rows; wave 0 reduces, one atomicAdd per block.
    if (wave == 0) {
        float v = 0.0f;
        if (lane < 16) {
            const int r = bid * 16 + lane;
            float s = 0.0f;
#pragma unroll
            for (int st = 0; st < NSTRIP; ++st) s += strip_sums[(size_t)st * TWOB + r];
            v = logf(s) - pos[r];
        }
        v += __shfl_xor(v, 1);
        v += __shfl_xor(v, 2);
        v += __shfl_xor(v, 4);
        v += __shfl_xor(v, 8);
        if (lane == 0) atomicAdd(loss_acc, v);
    }
    gbar(ctrl + 2);
    if (bid == 0 && tid == 0)
        out[0] = atomicAdd(loss_acc, 0.0f) / (float)TWOB;   // device-scope read
}

extern "C" void kernel_launch(void* const* d_in, const int* in_sizes, int n_in,
                              void* d_out, int out_size, void* d_ws, size_t ws_size,
                              hipStream_t stream) {
    const float* zi = (const float*)d_in[0];
    const float* zj = (const float*)d_in[1];
    // ws layout: zn (4 MB) | pos (32 KB) | strip_sums (256 KB) | ctrl (16 B)
    unsigned short* zn = (unsigned short*)d_ws;
    float* pos        = (float*)((char*)d_ws + (size_t)TWOB * DIM * 2);
    float* strip_sums = pos + TWOB;
    unsigned int* ctrl = (unsigned int*)(strip_sums + (size_t)NSTRIP * TWOB);
    float* out = (float*)d_out;

    hipMemsetAsync(ctrl, 0, 4 * sizeof(unsigned int), stream);  // barriers + loss = 0
    ntxent_fused<<<dim3(NBLK), 256, 0, stream>>>(zi, zj, zn, pos, strip_sums, ctrl, out);
}

// Round 10
// 109.434 us; speedup vs baseline: 1.9881x; 1.9881x over previous
//
#include <hip/hip_runtime.h>
#include <hip/hip_bf16.h>

#define B_ROWS 4096
#define TWOB   8192
#define DIM    256
#define INV_T  14.285714285714286f   // 1/0.07
#define EXPSCALE 20.609865074705232f // (1/0.07) * log2(e) -> exp2f

#define BM 128
#define BN 128
#define NSTRIP 16
#define CT_PER_STRIP 4    // (8192/128)/NSTRIP

typedef float f32x4 __attribute__((ext_vector_type(4)));

// ---------------- kernel 1: row L2-normalize, fp32 -> fp8 e4m3 (OCP) ----------------
// Also zeroes the finalize accumulators (ws is re-poisoned 0xAA before every launch).
__global__ __launch_bounds__(256) void normalize_k(const float* __restrict__ zi,
                                                   const float* __restrict__ zj,
                                                   unsigned char* __restrict__ zn,
                                                   float* __restrict__ loss_acc,
                                                   unsigned int* __restrict__ counter) {
    if (blockIdx.x == 0 && threadIdx.x == 0) {
        loss_acc[0] = 0.0f;
        counter[0]  = 0u;
    }
    int wave = threadIdx.x >> 6;
    int lane = threadIdx.x & 63;
    int row  = blockIdx.x * 4 + wave;             // 2048 blocks * 4 waves = 8192 rows
    const float* src = (row < B_ROWS) ? (zi + (size_t)row * DIM)
                                      : (zj + (size_t)(row - B_ROWS) * DIM);
    float4 v = reinterpret_cast<const float4*>(src)[lane];   // 64 lanes * 4 = 256
    float ss = v.x * v.x + v.y * v.y + v.z * v.z + v.w * v.w;
#pragma unroll
    for (int off = 32; off >= 1; off >>= 1) ss += __shfl_xor(ss, off);
    float inv = 1.0f / fmaxf(sqrtf(ss), 1e-8f);   // COS_EPS
    // pack 4 fp8 e4m3 bytes (gfx950 = OCP e4m3fn): bytes [x,y,z,w]
    int packed = 0;
    packed = __builtin_amdgcn_cvt_pk_fp8_f32(v.x * inv, v.y * inv, packed, false);
    packed = __builtin_amdgcn_cvt_pk_fp8_f32(v.z * inv, v.w * inv, packed, true);
    reinterpret_cast<int*>(zn)[(size_t)row * 64 + lane] = packed;
}

// ---------------- kernel 2: flash NT-Xent main, fp8 MFMA ----------------
// Grid: (64 row-tiles, 16 strips) = 1024 blocks (4 work/CU, ~3 resident).
// fp8 e4m3 halves all staging/LDS bytes vs bf16: A-tile resident = 32 KB,
// B ping-pong = 2x4 KB, total LDS ~41 KB -> 3 blocks/CU. Fragments are
// ds_read_b64 (vs b128), so the LDS pipe (~8.5 us) drops below the MFMA
// pipe (16.6 us) -> MFMA-bound. mfma_f32_16x16x32_fp8_fp8 runs at the bf16
// rate; C/D layout is dtype-independent, epilogue unchanged.
// Swizzle: 32B k-row = 2 x 16B units; u' = u ^ ((m>>2)&1) makes both the
// 16B-granule staging and the b64 fragment reads 2-way-max (free) in banks.
__global__ __launch_bounds__(256) void ntxent_main(const unsigned char* __restrict__ zn,
                                                   float* __restrict__ pos,
                                                   float* __restrict__ strip_sums) {
    __shared__ __attribute__((aligned(16))) unsigned char As[8][BM * 32];  // 8 kt x 4 KB = 32 KB
    __shared__ __attribute__((aligned(16))) unsigned char Bs[2][BN * 32];  // ping-pong, 8 KB
    __shared__ float rowsumL[2][BM];                                       // 1 KB

    const int tid  = threadIdx.x;
    const int wave = tid >> 6;
    const int lane = tid & 63;
    const int wr = wave >> 1, wc = wave & 1;
    const int quad = lane >> 4, lc = lane & 15;
    const int rt    = blockIdx.x;        // row-tile 0..63
    const int strip = blockIdx.y;        // 0..NSTRIP-1
    const int row0  = rt * BM;
    const int posTile = (rt + 32) & 63;  // col-tile holding (row+4096) mod 8192

    // staging: wave w stages 1 KB per 4 KB chunk: lane l -> 16B unit (w*64+l)
    //   m = w*32 + (l>>1), u = l&1, source su = u ^ ((m>>2)&1)
    const int m_st = wave * 32 + (lane >> 1);
    const int su   = (lane & 1) ^ ((m_st >> 2) & 1);
    const int stg_byte = m_st * 256 + su * 16;          // + tilebase*256 + kt*32
    const int lds_st   = wave * 1024 + lane * 16;       // + chunk base

    // fragment-read byte offsets within a 4 KB chunk (swizzle bit = (lc>>2)&1)
    const int uq   = (quad >> 1) ^ ((lc >> 2) & 1);
    const int aoff = lc * 32 + uq * 16 + (quad & 1) * 8;   // + wr*2048 + mi*512
    const int boff = lc * 32 + uq * 16 + (quad & 1) * 8;   // + wc*2048 + ni*512

    // ---- prologue: stage full A (8 chunks) + first B chunk ----
#pragma unroll
    for (int kt = 0; kt < 8; ++kt) {
        const unsigned char* ga = zn + (size_t)row0 * 256 + kt * 32 + stg_byte;
        __builtin_amdgcn_global_load_lds(
            (const __attribute__((address_space(1))) void*)ga,
            (__attribute__((address_space(3))) void*)((unsigned char*)As + kt * 4096 + lds_st), 16, 0, 0);
    }
    {
        const int col0 = strip * CT_PER_STRIP * BN;
        const unsigned char* gb = zn + (size_t)col0 * 256 + stg_byte;
        __builtin_amdgcn_global_load_lds(
            (const __attribute__((address_space(1))) void*)gb,
            (__attribute__((address_space(3))) void*)((unsigned char*)Bs + lds_st), 16, 0, 0);
    }

    f32x4 acc[4][4];
    float rsum[4][4];
#pragma unroll
    for (int mi = 0; mi < 4; ++mi)
#pragma unroll
        for (int r = 0; r < 4; ++r) rsum[mi][r] = 0.0f;

    for (int ct = 0; ct < CT_PER_STRIP; ++ct) {
        const int colTile = strip * CT_PER_STRIP + ct;
        const int col0 = colTile * BN;
#pragma unroll
        for (int mi = 0; mi < 4; ++mi)
#pragma unroll
            for (int ni = 0; ni < 4; ++ni) acc[mi][ni] = f32x4{0.f, 0.f, 0.f, 0.f};

#pragma unroll
        for (int kt = 0; kt < 8; ++kt) {
            // barrier: drains the B stage issued one iteration ago (covered by
            // that iteration's compute) and guards reuse of Bs[(kt+1)&1].
            __syncthreads();
            {
                const int nct = (kt == 7) ? ct + 1 : ct;
                const int nkt = (kt + 1) & 7;
                if (nct < CT_PER_STRIP) {
                    const int ncol0 = (strip * CT_PER_STRIP + nct) * BN;
                    const unsigned char* gb = zn + (size_t)ncol0 * 256 + nkt * 32 + stg_byte;
                    __builtin_amdgcn_global_load_lds(
                        (const __attribute__((address_space(1))) void*)gb,
                        (__attribute__((address_space(3))) void*)((unsigned char*)Bs + ((kt + 1) & 1) * 4096 + lds_st),
                        16, 0, 0);
                }
            }

            long af[4], bf[4];
#pragma unroll
            for (int mi = 0; mi < 4; ++mi)
                af[mi] = *(const long*)((const unsigned char*)As + kt * 4096 + wr * 2048 + mi * 512 + aoff);
#pragma unroll
            for (int ni = 0; ni < 4; ++ni)
                bf[ni] = *(const long*)((const unsigned char*)Bs + (kt & 1) * 4096 + wc * 2048 + ni * 512 + boff);
#pragma unroll
            for (int mi = 0; mi < 4; ++mi)
#pragma unroll
                for (int ni = 0; ni < 4; ++ni)
                    acc[mi][ni] = __builtin_amdgcn_mfma_f32_16x16x32_fp8_fp8(
                        af[mi], bf[ni], acc[mi][ni], 0, 0, 0);
        }

        // epilogue: exp + running row sums (C/D: row = quad*4+reg, col = lc).
        // Runs while the B(ct+1, kt=0) stage is in flight.
        const bool special = (colTile == rt) || (colTile == posTile);
#pragma unroll
        for (int mi = 0; mi < 4; ++mi) {
#pragma unroll
            for (int ni = 0; ni < 4; ++ni) {
                f32x4 a = acc[mi][ni];
#pragma unroll
                for (int r = 0; r < 4; ++r) {
                    float e = exp2f(a[r] * EXPSCALE);    // exp(s/T)
                    if (special) {
                        int gr = row0 + wr * 64 + mi * 16 + quad * 4 + r;
                        int gc = col0 + wc * 64 + ni * 16 + lc;
                        if (gc == ((gr + B_ROWS) & (TWOB - 1))) pos[gr] = a[r] * INV_T;
                        if (gr == gc) e = 0.0f;          // diagonal mask
                    }
                    rsum[mi][r] += e;
                }
            }
        }
    }

    // cross-lane: sum the 16 columns (low 4 lane bits) holding each row
#pragma unroll
    for (int mi = 0; mi < 4; ++mi) {
#pragma unroll
        for (int r = 0; r < 4; ++r) {
            float v = rsum[mi][r];
            v += __shfl_xor(v, 1);
            v += __shfl_xor(v, 2);
            v += __shfl_xor(v, 4);
            v += __shfl_xor(v, 8);
            if (lc == 0) rowsumL[wc][wr * 64 + mi * 16 + quad * 4 + r] = v;
        }
    }
    __syncthreads();
    if (tid < BM)
        strip_sums[(size_t)strip * TWOB + row0 + tid] = rowsumL[0][tid] + rowsumL[1][tid];
}

// ---------------- kernel 3: loss = mean(log(sumexp) - pos) ----------------
// 32 blocks x 256 threads, one row per thread. Device-scope atomic accumulation;
// last block to finish writes the mean. Accumulators zeroed by normalize_k.
__global__ __launch_bounds__(256) void finalize_k(const float* __restrict__ strip_sums,
                                                  const float* __restrict__ pos,
                                                  float* __restrict__ loss_acc,
                                                  unsigned int* __restrict__ counter,
                                                  float* __restrict__ out) {
    __shared__ float wsums[4];
    const int tid = threadIdx.x;
    const int r   = blockIdx.x * 256 + tid;
    float s = 0.0f;
#pragma unroll
    for (int st = 0; st < NSTRIP; ++st) s += strip_sums[(size_t)st * TWOB + r];
    float local = logf(s) - pos[r];
#pragma unroll
    for (int off = 32; off >= 1; off >>= 1) local += __shfl_xor(local, off);
    if ((tid & 63) == 0) wsums[tid >> 6] = local;
    __syncthreads();
    if (tid == 0) {
        float bsum = wsums[0] + wsums[1] + wsums[2] + wsums[3];
        atomicAdd(loss_acc, bsum);
        __threadfence();                              // order loss add before counter add
        unsigned int done = atomicAdd(counter, 1u);
        if (done == gridDim.x - 1) {
            float total = atomicAdd(loss_acc, 0.0f);  // device-scope atomic read
            out[0] = total / (float)TWOB;
        }
    }
}

extern "C" void kernel_launch(void* const* d_in, const int* in_sizes, int n_in,
                              void* d_out, int out_size, void* d_ws, size_t ws_size,
                              hipStream_t stream) {
    const float* zi = (const float*)d_in[0];
    const float* zj = (const float*)d_in[1];
    // ws layout: zn fp8 (2 MB) | pos (32 KB) | strip_sums (512 KB) | loss_acc | counter
    unsigned char* zn = (unsigned char*)d_ws;
    float* pos        = (float*)((char*)d_ws + (size_t)TWOB * DIM);
    float* strip_sums = pos + TWOB;
    float* loss_acc   = strip_sums + (size_t)NSTRIP * TWOB;
    unsigned int* counter = (unsigned int*)(loss_acc + 1);
    float* out = (float*)d_out;

    normalize_k<<<dim3(TWOB / 4), 256, 0, stream>>>(zi, zj, zn, loss_acc, counter);
    ntxent_main<<<dim3(64, NSTRIP), 256, 0, stream>>>(zn, pos, strip_sums);
    finalize_k<<<dim3(TWOB / 256), 256, 0, stream>>>(strip_sums, pos, loss_acc, counter, out);
}